// Round 2
// baseline (133.330 us; speedup 1.0000x reference)
//
#include <hip/hip_runtime.h>

// DatasetProjector: per-example Conv1d(200ch->512-of-4096, k=3, pad=1) + bias + GELU,
// computing only dataset_id[b]'s 512-channel slice (8x algebraic cut).
//
// R7 = R6 + occupancy decorrelation + coalesced epilogue:
//  - TT 256->128: 1024 blocks, __launch_bounds__(256,3) -> 3-4 blocks/CU (acc
//    halves to 64 VGPR, xs to 16.6KB). R4 proved cross-block overlap hides the
//    chunk-barrier drain; 2/CU phase-locks (same launch, same phase length), so
//    R6's pipeline fix bought little. More blocks at half the phase length
//    decorrelate.
//  - Epilogue now stages each 32-m slice through LDS (reusing xs, pitch 130 f32:
//    writes 2-way/free, reads conflict-free) and stores 512B-contiguous float2
//    wave-stores instead of 128 scalar dword stores/thread in 64B segments --
//    out is the largest HBM stream (64 MB).
//  - stage(c+1) moved to tap0 (2-tap slack before its only vmcnt wait); loadw
//    issued BEFORE stage inside the tap body so tap-boundary vmcnt waits cover
//    only the 4 W-frag loads, never the stage.
// X granule swizzle s = p ^ ((row>>1)&3) kept verbatim (R4 measured 0 conflicts).
// Note: ~78us/iter of total dur is harness d_ws/d_out re-poison fills (uncontrollable).

typedef unsigned short u16;
typedef __attribute__((ext_vector_type(8))) short bf16x8;
typedef __attribute__((ext_vector_type(4))) float f32x4;

#define CIN 200
#define CINP 224        // padded channels = 7 chunks of 32
#define T 1024
#define BATCH 32
#define MD 512
#define XT_ROWS 1026    // row t1 = t+1; rows 0 and 1025 are zeros
#define NCHUNK 7
#define XP_PITCH 202    // prep LDS pitch in u16 -> 101 dwords (odd => conflict-free)
#define TT 128          // t-tile
#define XROWS (TT + 2)  // 130 staged x rows (t0-1 .. t0+128)
#define XGRAN (XROWS * 4)     // 520 16B granules = 8.3 KB per buffer
#define EP_PITCH 130          // epilogue LDS pitch in f32 (130 % 32 == 2 -> <=2-way)
#define WOB 256               // 4096/16 o-blocks
#define WF_PER_OB (21 * 512)  // 3 taps x 7 chunks x 64 lanes x 8 u16 = 10752 u16/oblk

__device__ __forceinline__ u16 f2bf(float f) {
    unsigned u = __float_as_uint(f);
    u += 0x7FFFu + ((u >> 16) & 1u);   // RNE
    return (u16)(u >> 16);
}

// async global(16B) -> LDS, dest = wave-uniform base + lane*16
__device__ __forceinline__ void g2l16(void* lds, const void* g) {
    __builtin_amdgcn_global_load_lds(
        (const __attribute__((address_space(1))) unsigned int*)(uintptr_t)g,
        (__attribute__((address_space(3))) unsigned int*)(unsigned)(uintptr_t)lds,
        16, 0, 0);
}

// ---- fused prep: blocks [0,512) transpose x -> xt[b][t+1][224] bf16;
//      blocks [512, 512+256) transform W[o][i][k] -> wf fragment-ordered bf16 ----
__global__ __launch_bounds__(256) void prep(const float* __restrict__ x,
                                            const float* __restrict__ W,
                                            u16* __restrict__ xt,
                                            u16* __restrict__ wf) {
    __shared__ __align__(16) unsigned char smem[16 * 673 * 4];  // 43 KB, unioned
    const int tid = threadIdx.x;
    if (blockIdx.x < 512) {
        u16* tile = (u16*)smem;   // uses 64*202*2 = 25.9 KB of smem
        const int b  = blockIdx.x >> 4;
        const int bx = blockIdx.x & 15;
        const int t0 = bx * 64;
        const int tl = tid & 63;       // t within tile (lane -> coalesced x reads)
        const int w  = tid >> 6;
        const float* xb = x + (size_t)b * CIN * T + t0 + tl;
        for (int i = w; i < CIN; i += 4)                 // LDS row pitch 101 dwords (odd) -> conflict-free
            tile[tl * XP_PITCH + i] = f2bf(xb[(size_t)i * T]);
        __syncthreads();
        u16* xrow = xt + ((size_t)b * XT_ROWS + 1 + t0) * CINP;
        for (int it = 0; it < 16; ++it) {
            int r = it * 4 + w;
            if (tl < 56) {                               // 56 lanes x ushort4 = 224 ch
                ushort4 v = {0, 0, 0, 0};
                if (tl < 50) {                           // 50*4 = 200 valid channels
                    const u16* p = tile + r * XP_PITCH + tl * 4;
                    v.x = p[0]; v.y = p[1]; v.z = p[2]; v.w = p[3];
                }
                *(ushort4*)(xrow + (size_t)r * CINP + tl * 4) = v;
            }
        }
        if (bx == 0 && tid < 112)
            ((unsigned*)(xt + (size_t)b * XT_ROWS * CINP))[tid] = 0;          // t = -1 row
        if (bx == 15 && tid < 112)
            ((unsigned*)(xt + ((size_t)b * XT_ROWS + 1025) * CINP))[tid] = 0; // t = 1024 row
    } else {
        // W -> wf: one block per oblk (16 o-rows). Coalesced f32 load -> LDS ->
        // fully-coalesced u16 store in fragment order.
        float* wtile = (float*)smem;                     // [16][673] padded (673%32==1)
        const int ob = blockIdx.x - 512;
        const float* wp = W + (size_t)ob * 16 * 768;     // W rows o in [ob*16, ob*16+16)
        for (int j = tid; j < 16 * 672; j += 256) {      // only i<224 (first 672 f32/row) used
            int o = j / 672, r = j - o * 672;
            wtile[o * 673 + r] = wp[(size_t)o * 768 + r];
        }
        __syncthreads();
        u16* wo = wf + (size_t)ob * WF_PER_OB;
        for (int j = tid; j < WF_PER_OB; j += 256) {     // j = ((k*7+c)*64+lane)*8+e
            int e    = j & 7;
            int lane = (j >> 3) & 63;
            int kc   = j >> 9;                           // k*7 + c  (< 21)
            int cc   = kc % 7, k = kc / 7;
            int l = lane & 15, q = lane >> 4;
            int i = cc * 32 + q * 8 + e;                 // channel index
            // A-fragment semantics: lane (l,q) holds A[row=l][K=q*8+e] of o-row ob*16+l
            wo[j] = f2bf(wtile[l * 673 + i * 3 + k]);
        }
    }
}

// ---- main: per-example MFMA conv-GEMM, 128m x 128t per block, 1024 blocks ----
__global__ __launch_bounds__(256, 3) void conv_mfma(const u16* __restrict__ xt,
                                                    const u16* __restrict__ wf,
                                                    const int* __restrict__ dsid,
                                                    const float* __restrict__ bias,
                                                    float* __restrict__ out) {
    __shared__ __align__(16) u16 xs[2 * XGRAN * 8];    // 16.6 KB: double-buffered X

    const int tid = threadIdx.x;
    const int wave = tid >> 6, lane = tid & 63;
    const int l = lane & 15, quad = lane >> 4;
    const int wm  = (wave & 1) * 64;       // wave m offset (2 m-waves)
    const int wti = (wave >> 1) * 64;      // wave t offset (2 t-waves)

    // XCD-aware swizzle: ids {k, k+8, k+16, k+24} = the 4 m-blocks of one (b,t)
    // -> same (id % 8) -> same XCD -> xt slice fetched once per XCD.
    const int id = blockIdx.x;                 // 1024 = 32 groups x 4 m x 8 tb-members
    const int tb = (id >> 5) * 8 + (id & 7);   // 0..255 = (b, tloc)
    const int m0 = ((id >> 3) & 3) * 128;
    const int t0 = (tb & 7) * TT;
    const int b  = tb >> 3;
    const int d  = dsid[b];
    const int obase = d * MD + m0;

    f32x4 acc[4][4];
#pragma unroll
    for (int mi = 0; mi < 4; ++mi)
#pragma unroll
        for (int ti = 0; ti < 4; ++ti) acc[mi][ti] = (f32x4){0.f, 0.f, 0.f, 0.f};

    const u16* xbase = xt + ((size_t)b * XT_ROWS + t0) * CINP;  // row r -> t = t0+r-1
    // wave-uniform oblk base + per-lane 16B: each LOADW is one coalesced 1KB dwordx4
    const u16* wfw = wf + (size_t)((obase + wm) >> 4) * WF_PER_OB + lane * 8;

    // hoisted X staging addresses (chunk-invariant); chunk advance = +32 u16 = 64 B
    const u16* xsrc[3]; u16* xdst[3];
#pragma unroll
    for (int k = 0; k < 3; ++k) {
        int g = tid + k * 256;
        int r = g >> 2, p = g & 3, s = p ^ ((r >> 1) & 3);
        if (g < XGRAN) { xsrc[k] = xbase + (size_t)r * CINP + s * 8; xdst[k] = xs + (size_t)(g & ~63) * 8; }
        else           { xsrc[k] = xbase;                            xdst[k] = xs; }
    }

    auto stage = [&](int bsel, int c) {
        const int ic  = c * 32;
        const int off = bsel * (XGRAN * 8);
#pragma unroll
        for (int k = 0; k < 3; ++k)
            if (tid + k * 256 < XGRAN) g2l16(xdst[k] + off, xsrc[k] + ic);
    };
    auto loadw = [&](bf16x8* dst, int tap, int c) {
#pragma unroll
        for (int mi = 0; mi < 4; ++mi)
            dst[mi] = *(const bf16x8*)(wfw + (size_t)((mi * 21 + tap * 7 + c) << 9));
    };

    bf16x8 acur[4], anxt[4];
    stage(0, 0);
    loadw(acur, 0, 0);
    __syncthreads();   // drains vmcnt(0): buf0 + first A-frags ready

#pragma unroll
    for (int c = 0; c < NCHUNK; ++c) {
        const int bsel = c & 1;
        const u16* xb = xs + bsel * (XGRAN * 8);
#pragma unroll
        for (int tap = 0; tap < 3; ++tap) {
            // loadw FIRST: the next tap's vmcnt wait then covers only these 4
            // loads, never the stage (stage drains 2 taps later / at the barrier).
            if (!(tap == 2 && c == NCHUNK - 1))
                loadw(anxt, (tap == 2 ? 0 : tap + 1), (tap == 2 ? c + 1 : c));
            if (tap == 0 && c + 1 < NCHUNK) stage(bsel ^ 1, c + 1);
#pragma unroll
            for (int ti = 0; ti < 4; ++ti) {
                int row = wti + tap + ti * 16 + l;
                bf16x8 bv = *(const bf16x8*)(xb + ((size_t)row * 4 + (quad ^ ((row >> 1) & 3))) * 8);
                __builtin_amdgcn_s_setprio(1);
#pragma unroll
                for (int mi = 0; mi < 4; ++mi)
                    acc[mi][ti] = __builtin_amdgcn_mfma_f32_16x16x32_bf16(acur[mi], bv, acc[mi][ti], 0, 0, 0);
                __builtin_amdgcn_s_setprio(0);
            }
#pragma unroll
            for (int mi = 0; mi < 4; ++mi) acur[mi] = anxt[mi];   // renamed away by unroll
        }
        if (c + 1 < NCHUNK) __syncthreads();   // single barrier/chunk
    }

    // ---- epilogue: bias + GELU in regs, LDS-transpose 32-m slices, 512B stores ----
    float bvv[4][4];
#pragma unroll
    for (int mi = 0; mi < 4; ++mi)
#pragma unroll
        for (int r = 0; r < 4; ++r)
            bvv[mi][r] = bias[obase + wm + mi * 16 + quad * 4 + r];

    float* ep = (float*)xs;    // 32 x EP_PITCH f32 = 16640 B = exactly sizeof(xs)
    const int myhalf = wave & 1;
#pragma unroll
    for (int p = 0; p < 4; ++p) {          // pass p covers m-local [32p, 32p+32)
        __syncthreads();                   // prev pass reads done / compute done
        if ((p >> 1) == myhalf) {
#pragma unroll
            for (int j = 0; j < 2; ++j) {
                int mi = 2 * (p & 1) + j;
#pragma unroll
                for (int ti = 0; ti < 4; ++ti) {
#pragma unroll
                    for (int r = 0; r < 4; ++r) {
                        float v = acc[mi][ti][r] + bvv[mi][r];
                        float p2 = v * v;
                        // exp(-z), z = v*(1.59577 + 0.0713548 v^2), folded to exp2
                        float z2 = v * fmaf(p2, -0.10295089f, -2.30243665f);
                        float e = __builtin_amdgcn_exp2f(z2);
                        float g = v * __builtin_amdgcn_rcpf(1.0f + e);   // v * sigmoid(z)
                        ep[(j * 16 + quad * 4 + r) * EP_PITCH + wti + ti * 16 + l] = g;
                    }
                }
            }
        }
        __syncthreads();
        // 32 rows x 128 t: wave w stores rows [8w, 8w+8), 512 B contiguous each
#pragma unroll
        for (int rr = 0; rr < 8; ++rr) {
            int row = wave * 8 + rr;
            float2 v = *(const float2*)(ep + row * EP_PITCH + lane * 2);
            *(float2*)(out + ((size_t)(b * MD + m0 + p * 32 + row)) * T + t0 + lane * 2) = v;
        }
    }
}

extern "C" void kernel_launch(void* const* d_in, const int* in_sizes, int n_in,
                              void* d_out, int out_size, void* d_ws, size_t ws_size,
                              hipStream_t stream) {
    const float* x    = (const float*)d_in[0];
    const int*   dsid = (const int*)d_in[1];
    const float* W    = (const float*)d_in[2];
    const float* bias = (const float*)d_in[3];
    float* out = (float*)d_out;

    u16* xt = (u16*)d_ws;                                // 32*1026*224*2 = 14.7 MB
    u16* wf = xt + (size_t)BATCH * XT_ROWS * CINP;       // 256*21*512*2  =  5.5 MB

    prep<<<512 + WOB, 256, 0, stream>>>(x, W, xt, wf);
    conv_mfma<<<1024, 256, 0, stream>>>(xt, wf, dsid, bias, out);
}

// Round 3
// 123.223 us; speedup vs baseline: 1.0820x; 1.0820x over previous
//
#include <hip/hip_runtime.h>

// DatasetProjector: per-example Conv1d(200ch->512-of-4096, k=3, pad=1) + bias + GELU,
// computing only dataset_id[b]'s 512-channel slice (8x algebraic cut).
//
// R8 = R6 shape (TT=256, 512 blocks, 2/CU, scalar-store epilogue) + T3/T4
// counted-vmcnt chunk schedule. R7 post-mortem: TT=128 was latency-bound
// (MfmaUtil 13%: 16-MFMA taps can't hide ~300cy W L2 latency; 2x W traffic).
// Changes vs R6:
//  - Chunk barrier is raw s_barrier preceded by inline-asm `s_waitcnt vmcnt(4)`:
//    drains exactly the 5 X-stage loads (oldest) while leaving the 4 just-issued
//    next-chunk W loads in flight. No more full vmcnt(0) drain per chunk.
//  - X-stage(c+1) issues at tap0 (not tap2): cover grows ~300 -> ~900+ cyc
//    (survives HBM-miss latency on first-toucher blocks).
//  - All 3 taps' W fragments issue at tap0 (w1,w2 get 1-2 taps cover); next
//    chunk's tap0 W loads directly into acur at tap2 (register reuse, W regs=48).
//    In-order vmem completion => compiler's auto-waits for w1/w2 never force a
//    stage drain (stage is older than nothing they wait on).
//  - Race check (sync edit): stage(c+1) overwrites the buffer read in chunk c-1;
//    each wave consumed those ds_reads before reaching the c-1 -> c barrier, and
//    stage issues after it. Manual vmcnt(4): per-wave outstanding at barrier =
//    stage(4|5, oldest) + nextW(4, newest) -> drains all stage loads every wave.
// X granule swizzle s = p ^ ((row>>1)&3) kept verbatim (R4 measured 0 conflicts).
// Note: ~78us/iter of total dur is harness d_ws/d_out re-poison fills (uncontrollable).

typedef unsigned short u16;
typedef __attribute__((ext_vector_type(8))) short bf16x8;
typedef __attribute__((ext_vector_type(4))) float f32x4;

#define CIN 200
#define CINP 224        // padded channels = 7 chunks of 32
#define T 1024
#define BATCH 32
#define MD 512
#define XT_ROWS 1026    // row t1 = t+1; rows 0 and 1025 are zeros
#define NCHUNK 7
#define XP_PITCH 202    // prep LDS pitch in u16 -> 101 dwords (odd => conflict-free)
#define TT 256          // t-tile
#define XROWS (TT + 2)  // 258 staged x rows (t0-1 .. t0+256)
#define XGRAN (XROWS * 4)     // 1032 16B granules = 16.5 KB per buffer
#define WOB 256               // 4096/16 o-blocks
#define WF_PER_OB (21 * 512)  // 3 taps x 7 chunks x 64 lanes x 8 u16 = 10752 u16/oblk

__device__ __forceinline__ u16 f2bf(float f) {
    unsigned u = __float_as_uint(f);
    u += 0x7FFFu + ((u >> 16) & 1u);   // RNE
    return (u16)(u >> 16);
}

// async global(16B) -> LDS, dest = wave-uniform base + lane*16
__device__ __forceinline__ void g2l16(void* lds, const void* g) {
    __builtin_amdgcn_global_load_lds(
        (const __attribute__((address_space(1))) unsigned int*)(uintptr_t)g,
        (__attribute__((address_space(3))) unsigned int*)(unsigned)(uintptr_t)lds,
        16, 0, 0);
}

// ---- fused prep: blocks [0,512) transpose x -> xt[b][t+1][224] bf16;
//      blocks [512, 512+256) transform W[o][i][k] -> wf fragment-ordered bf16 ----
__global__ __launch_bounds__(256) void prep(const float* __restrict__ x,
                                            const float* __restrict__ W,
                                            u16* __restrict__ xt,
                                            u16* __restrict__ wf) {
    __shared__ __align__(16) unsigned char smem[16 * 673 * 4];  // 43 KB, unioned
    const int tid = threadIdx.x;
    if (blockIdx.x < 512) {
        u16* tile = (u16*)smem;   // uses 64*202*2 = 25.9 KB of smem
        const int b  = blockIdx.x >> 4;
        const int bx = blockIdx.x & 15;
        const int t0 = bx * 64;
        const int tl = tid & 63;       // t within tile (lane -> coalesced x reads)
        const int w  = tid >> 6;
        const float* xb = x + (size_t)b * CIN * T + t0 + tl;
        for (int i = w; i < CIN; i += 4)                 // LDS row pitch 101 dwords (odd) -> conflict-free
            tile[tl * XP_PITCH + i] = f2bf(xb[(size_t)i * T]);
        __syncthreads();
        u16* xrow = xt + ((size_t)b * XT_ROWS + 1 + t0) * CINP;
        for (int it = 0; it < 16; ++it) {
            int r = it * 4 + w;
            if (tl < 56) {                               // 56 lanes x ushort4 = 224 ch
                ushort4 v = {0, 0, 0, 0};
                if (tl < 50) {                           // 50*4 = 200 valid channels
                    const u16* p = tile + r * XP_PITCH + tl * 4;
                    v.x = p[0]; v.y = p[1]; v.z = p[2]; v.w = p[3];
                }
                *(ushort4*)(xrow + (size_t)r * CINP + tl * 4) = v;
            }
        }
        if (bx == 0 && tid < 112)
            ((unsigned*)(xt + (size_t)b * XT_ROWS * CINP))[tid] = 0;          // t = -1 row
        if (bx == 15 && tid < 112)
            ((unsigned*)(xt + ((size_t)b * XT_ROWS + 1025) * CINP))[tid] = 0; // t = 1024 row
    } else {
        // W -> wf: one block per oblk (16 o-rows). Coalesced f32 load -> LDS ->
        // fully-coalesced u16 store in fragment order.
        float* wtile = (float*)smem;                     // [16][673] padded (673%32==1)
        const int ob = blockIdx.x - 512;
        const float* wp = W + (size_t)ob * 16 * 768;     // W rows o in [ob*16, ob*16+16)
        for (int j = tid; j < 16 * 672; j += 256) {      // only i<224 (first 672 f32/row) used
            int o = j / 672, r = j - o * 672;
            wtile[o * 673 + r] = wp[(size_t)o * 768 + r];
        }
        __syncthreads();
        u16* wo = wf + (size_t)ob * WF_PER_OB;
        for (int j = tid; j < WF_PER_OB; j += 256) {     // j = ((k*7+c)*64+lane)*8+e
            int e    = j & 7;
            int lane = (j >> 3) & 63;
            int kc   = j >> 9;                           // k*7 + c  (< 21)
            int cc   = kc % 7, k = kc / 7;
            int l = lane & 15, q = lane >> 4;
            int i = cc * 32 + q * 8 + e;                 // channel index
            // A-fragment semantics: lane (l,q) holds A[row=l][K=q*8+e] of o-row ob*16+l
            wo[j] = f2bf(wtile[l * 673 + i * 3 + k]);
        }
    }
}

// ---- main: per-example MFMA conv-GEMM, 128m x 256t per block, 512 blocks ----
__global__ __launch_bounds__(256, 2) void conv_mfma(const u16* __restrict__ xt,
                                                    const u16* __restrict__ wf,
                                                    const int* __restrict__ dsid,
                                                    const float* __restrict__ bias,
                                                    float* __restrict__ out) {
    __shared__ __align__(16) u16 xs[2 * XGRAN * 8];    // 33 KB: double-buffered X

    const int tid = threadIdx.x;
    const int wave = tid >> 6, lane = tid & 63;
    const int l = lane & 15, quad = lane >> 4;
    const int wm  = (wave & 1) * 64;       // wave m offset (2 m-waves)
    const int wti = (wave >> 1) * 128;     // wave t offset (2 t-waves)

    // XCD-aware swizzle: ids {k, k+8, k+16, k+24} = the 4 m-blocks of one (b,t)
    // -> same (id % 8) -> same XCD -> xt slice fetched once per XCD.
    const int id = blockIdx.x;
    const int tb = (id >> 5) * 8 + (id & 7);   // 0..127 = (b, tloc)
    const int m0 = ((id >> 3) & 3) * 128;
    const int t0 = (tb & 3) * TT;
    const int b  = tb >> 2;
    const int d  = dsid[b];
    const int obase = d * MD + m0;

    f32x4 acc[4][8];
#pragma unroll
    for (int mi = 0; mi < 4; ++mi)
#pragma unroll
        for (int ti = 0; ti < 8; ++ti) acc[mi][ti] = (f32x4){0.f, 0.f, 0.f, 0.f};

    const u16* xbase = xt + ((size_t)b * XT_ROWS + t0) * CINP;  // row r -> t = t0+r-1
    // wave-uniform oblk base + per-lane 16B: each LOADW is one coalesced 1KB dwordx4
    const u16* wfw = wf + (size_t)((obase + wm) >> 4) * WF_PER_OB + lane * 8;

    // hoisted X staging addresses (chunk-invariant); chunk advance = +32 u16 = 64 B
    const u16* xsrc[5]; u16* xdst[5];
#pragma unroll
    for (int k = 0; k < 5; ++k) {
        int g = tid + k * 256;
        int r = g >> 2, p = g & 3, s = p ^ ((r >> 1) & 3);
        if (g < XGRAN) { xsrc[k] = xbase + (size_t)r * CINP + s * 8; xdst[k] = xs + (size_t)(g & ~63) * 8; }
        else           { xsrc[k] = xbase;                            xdst[k] = xs; }
    }

    auto stage = [&](int bsel, int c) {
        const int ic  = c * 32;
        const int off = bsel * (XGRAN * 8);
#pragma unroll
        for (int k = 0; k < 5; ++k)
            if (tid + k * 256 < XGRAN) g2l16(xdst[k] + off, xsrc[k] + ic);
    };
    auto loadw = [&](bf16x8* dst, int tap, int c) {
#pragma unroll
        for (int mi = 0; mi < 4; ++mi)
            dst[mi] = *(const bf16x8*)(wfw + (size_t)((mi * 21 + tap * 7 + c) << 9));
    };

    bf16x8 acur[4], w1[4], w2[4];
    stage(0, 0);
    loadw(acur, 0, 0);
    __syncthreads();   // prologue: full drain once (buf0 + first A-frags ready)

#pragma unroll
    for (int c = 0; c < NCHUNK; ++c) {
        const u16* xb = xs + (c & 1) * (XGRAN * 8);
        // Issue order matters (in-order vmem completion):
        //   w1(4), w2(4)  [oldest]  ->  stage(4|5)  ->  [tap2] next acur(4) [newest]
        // so auto-waits for w1/w2 never drain stage, and the manual vmcnt(4)
        // at the barrier drains exactly stage while leaving next-acur in flight.
        loadw(w1, 1, c);
        loadw(w2, 2, c);
        if (c + 1 < NCHUNK) stage((c & 1) ^ 1, c + 1);

#pragma unroll
        for (int tap = 0; tap < 3; ++tap) {
            const bf16x8* af = (tap == 0) ? acur : (tap == 1) ? w1 : w2;
            if (tap == 2 && c + 1 < NCHUNK) loadw(acur, 0, c + 1);  // direct into acur (dead)
#pragma unroll
            for (int ti = 0; ti < 8; ++ti) {
                int row = wti + tap + ti * 16 + l;
                bf16x8 bv = *(const bf16x8*)(xb + ((size_t)row * 4 + (quad ^ ((row >> 1) & 3))) * 8);
                __builtin_amdgcn_s_setprio(1);
#pragma unroll
                for (int mi = 0; mi < 4; ++mi)
                    acc[mi][ti] = __builtin_amdgcn_mfma_f32_16x16x32_bf16(af[mi], bv, acc[mi][ti], 0, 0, 0);
                __builtin_amdgcn_s_setprio(0);
            }
        }

        if (c + 1 < NCHUNK) {
            // counted drain: stage loads (oldest) done; next-chunk W (newest, <=4) may fly
            asm volatile("s_waitcnt vmcnt(4)" ::: "memory");
            __builtin_amdgcn_s_barrier();
            __builtin_amdgcn_sched_barrier(0);
        }
    }

    // epilogue: +bias, sigmoid-form tanh-GELU (exp2-folded, branchless), f32 store
#pragma unroll
    for (int mi = 0; mi < 4; ++mi) {
        float bvv[4];
#pragma unroll
        for (int r = 0; r < 4; ++r)
            bvv[r] = bias[obase + wm + mi * 16 + quad * 4 + r];
#pragma unroll
        for (int ti = 0; ti < 8; ++ti) {
            int t = t0 + wti + ti * 16 + l;
#pragma unroll
            for (int r = 0; r < 4; ++r) {
                int m = wm + mi * 16 + quad * 4 + r;
                float v = acc[mi][ti][r] + bvv[r];
                float p2 = v * v;
                // exp(-z), z = v*(1.59577 + 0.0713548 v^2), folded to exp2
                float z2 = v * fmaf(p2, -0.10295089f, -2.30243665f);
                float e = __builtin_amdgcn_exp2f(z2);
                float g = v * __builtin_amdgcn_rcpf(1.0f + e);   // v * sigmoid(z)
                out[((size_t)(b * MD + m0 + m)) * T + t] = g;
            }
        }
    }
}

extern "C" void kernel_launch(void* const* d_in, const int* in_sizes, int n_in,
                              void* d_out, int out_size, void* d_ws, size_t ws_size,
                              hipStream_t stream) {
    const float* x    = (const float*)d_in[0];
    const int*   dsid = (const int*)d_in[1];
    const float* W    = (const float*)d_in[2];
    const float* bias = (const float*)d_in[3];
    float* out = (float*)d_out;

    u16* xt = (u16*)d_ws;                                // 32*1026*224*2 = 14.7 MB
    u16* wf = xt + (size_t)BATCH * XT_ROWS * CINP;       // 256*21*512*2  =  5.5 MB

    prep<<<512 + WOB, 256, 0, stream>>>(x, W, xt, wf);
    conv_mfma<<<512, 256, 0, stream>>>(xt, wf, dsid, bias, out);
}

// Round 4
// 123.072 us; speedup vs baseline: 1.0833x; 1.0012x over previous
//
#include <hip/hip_runtime.h>

// DatasetProjector: per-example Conv1d(200ch->512-of-4096, k=3, pad=1) + bias + GELU,
// computing only dataset_id[b]'s 512-channel slice (8x algebraic cut).
//
// R9 = R8 + XCD regroup for W L2-residency. R8 post-mortem: three schedule
// attacks (R6 pipeline, R7 occupancy, R8 counted-vmcnt) all null -> conv is not
// schedule-bound; R7's direct counters (MfmaUtil 13%, FETCH 46MB) point at W.
// Old swizzle put 16 distinct b's on each XCD -> per-XCD W working set ~5.2MB >
// 4MB L2 -> W stream thrashes (HBM-miss tap loads ~900cy vs the ~1200cy 1-tap
// prefetch cover; extra ~20MB HBM fetch). New mapping: each XCD owns 4 complete
// b's (64 blocks = 4b x 4m x 4t): W per XCD <= 4d x 4m0 x 172KB = 2.75MB (L2-hot),
// xt quads still XCD-local (fetched once per slice).
// Chunk schedule (R8, kept): counted s_waitcnt vmcnt(4) + raw s_barrier per
// chunk (drains the 5 X-stage loads, leaves 4 next-chunk W loads in flight);
// stage(c+1) at tap0; all 3 taps' W at tap0; next tap0-W direct into acur.
// X granule swizzle s = p ^ ((row>>1)&3) kept verbatim (R4 measured 0 conflicts).
// Note: ~78us/iter of total dur is harness d_ws/d_out re-poison fills (uncontrollable).

typedef unsigned short u16;
typedef __attribute__((ext_vector_type(8))) short bf16x8;
typedef __attribute__((ext_vector_type(4))) float f32x4;

#define CIN 200
#define CINP 224        // padded channels = 7 chunks of 32
#define T 1024
#define BATCH 32
#define MD 512
#define XT_ROWS 1026    // row t1 = t+1; rows 0 and 1025 are zeros
#define NCHUNK 7
#define XP_PITCH 202    // prep LDS pitch in u16 -> 101 dwords (odd => conflict-free)
#define TT 256          // t-tile
#define XROWS (TT + 2)  // 258 staged x rows (t0-1 .. t0+256)
#define XGRAN (XROWS * 4)     // 1032 16B granules = 16.5 KB per buffer
#define WOB 256               // 4096/16 o-blocks
#define WF_PER_OB (21 * 512)  // 3 taps x 7 chunks x 64 lanes x 8 u16 = 10752 u16/oblk

__device__ __forceinline__ u16 f2bf(float f) {
    unsigned u = __float_as_uint(f);
    u += 0x7FFFu + ((u >> 16) & 1u);   // RNE
    return (u16)(u >> 16);
}

// async global(16B) -> LDS, dest = wave-uniform base + lane*16
__device__ __forceinline__ void g2l16(void* lds, const void* g) {
    __builtin_amdgcn_global_load_lds(
        (const __attribute__((address_space(1))) unsigned int*)(uintptr_t)g,
        (__attribute__((address_space(3))) unsigned int*)(unsigned)(uintptr_t)lds,
        16, 0, 0);
}

// ---- fused prep: blocks [0,512) transpose x -> xt[b][t+1][224] bf16;
//      blocks [512, 512+256) transform W[o][i][k] -> wf fragment-ordered bf16 ----
__global__ __launch_bounds__(256) void prep(const float* __restrict__ x,
                                            const float* __restrict__ W,
                                            u16* __restrict__ xt,
                                            u16* __restrict__ wf) {
    __shared__ __align__(16) unsigned char smem[16 * 673 * 4];  // 43 KB, unioned
    const int tid = threadIdx.x;
    if (blockIdx.x < 512) {
        u16* tile = (u16*)smem;   // uses 64*202*2 = 25.9 KB of smem
        const int b  = blockIdx.x >> 4;
        const int bx = blockIdx.x & 15;
        const int t0 = bx * 64;
        const int tl = tid & 63;       // t within tile (lane -> coalesced x reads)
        const int w  = tid >> 6;
        const float* xb = x + (size_t)b * CIN * T + t0 + tl;
        for (int i = w; i < CIN; i += 4)                 // LDS row pitch 101 dwords (odd) -> conflict-free
            tile[tl * XP_PITCH + i] = f2bf(xb[(size_t)i * T]);
        __syncthreads();
        u16* xrow = xt + ((size_t)b * XT_ROWS + 1 + t0) * CINP;
        for (int it = 0; it < 16; ++it) {
            int r = it * 4 + w;
            if (tl < 56) {                               // 56 lanes x ushort4 = 224 ch
                ushort4 v = {0, 0, 0, 0};
                if (tl < 50) {                           // 50*4 = 200 valid channels
                    const u16* p = tile + r * XP_PITCH + tl * 4;
                    v.x = p[0]; v.y = p[1]; v.z = p[2]; v.w = p[3];
                }
                *(ushort4*)(xrow + (size_t)r * CINP + tl * 4) = v;
            }
        }
        if (bx == 0 && tid < 112)
            ((unsigned*)(xt + (size_t)b * XT_ROWS * CINP))[tid] = 0;          // t = -1 row
        if (bx == 15 && tid < 112)
            ((unsigned*)(xt + ((size_t)b * XT_ROWS + 1025) * CINP))[tid] = 0; // t = 1024 row
    } else {
        // W -> wf: one block per oblk (16 o-rows). Coalesced f32 load -> LDS ->
        // fully-coalesced u16 store in fragment order.
        float* wtile = (float*)smem;                     // [16][673] padded (673%32==1)
        const int ob = blockIdx.x - 512;
        const float* wp = W + (size_t)ob * 16 * 768;     // W rows o in [ob*16, ob*16+16)
        for (int j = tid; j < 16 * 672; j += 256) {      // only i<224 (first 672 f32/row) used
            int o = j / 672, r = j - o * 672;
            wtile[o * 673 + r] = wp[(size_t)o * 768 + r];
        }
        __syncthreads();
        u16* wo = wf + (size_t)ob * WF_PER_OB;
        for (int j = tid; j < WF_PER_OB; j += 256) {     // j = ((k*7+c)*64+lane)*8+e
            int e    = j & 7;
            int lane = (j >> 3) & 63;
            int kc   = j >> 9;                           // k*7 + c  (< 21)
            int cc   = kc % 7, k = kc / 7;
            int l = lane & 15, q = lane >> 4;
            int i = cc * 32 + q * 8 + e;                 // channel index
            // A-fragment semantics: lane (l,q) holds A[row=l][K=q*8+e] of o-row ob*16+l
            wo[j] = f2bf(wtile[l * 673 + i * 3 + k]);
        }
    }
}

// ---- main: per-example MFMA conv-GEMM, 128m x 256t per block, 512 blocks ----
__global__ __launch_bounds__(256, 2) void conv_mfma(const u16* __restrict__ xt,
                                                    const u16* __restrict__ wf,
                                                    const int* __restrict__ dsid,
                                                    const float* __restrict__ bias,
                                                    float* __restrict__ out) {
    __shared__ __align__(16) u16 xs[2 * XGRAN * 8];    // 33 KB: double-buffered X

    const int tid = threadIdx.x;
    const int wave = tid >> 6, lane = tid & 63;
    const int l = lane & 15, quad = lane >> 4;
    const int wm  = (wave & 1) * 64;       // wave m offset (2 m-waves)
    const int wti = (wave >> 1) * 128;     // wave t offset (2 t-waves)

    // XCD regroup: dispatch round-robins id%8 across XCDs, so give XCD k the
    // blocks {id : id&7 == k} = 4 COMPLETE b's (4b x 4m x 4t = 64 blocks).
    // Per-XCD working set: W <= 4d x 4m0 x 172KB = 2.75MB (L2-hot, was ~5.2MB
    // thrashing) + xt 4 x 460KB. Same-(b,t) m-quads still same-XCD (ids differ
    // by 32/64/96 -> same id&7) -> xt slice fetched once per XCD, as before.
    const int id  = blockIdx.x;          // 512 = 8 xcd x 4 b x 4 m x 4 t
    const int xcd = id & 7;
    const int j   = id >> 3;             // 0..63 within XCD
    const int b   = xcd * 4 + (j >> 4);
    const int m0  = ((j >> 2) & 3) * 128;
    const int t0  = (j & 3) * TT;
    const int d  = dsid[b];
    const int obase = d * MD + m0;

    f32x4 acc[4][8];
#pragma unroll
    for (int mi = 0; mi < 4; ++mi)
#pragma unroll
        for (int ti = 0; ti < 8; ++ti) acc[mi][ti] = (f32x4){0.f, 0.f, 0.f, 0.f};

    const u16* xbase = xt + ((size_t)b * XT_ROWS + t0) * CINP;  // row r -> t = t0+r-1
    // wave-uniform oblk base + per-lane 16B: each LOADW is one coalesced 1KB dwordx4
    const u16* wfw = wf + (size_t)((obase + wm) >> 4) * WF_PER_OB + lane * 8;

    // hoisted X staging addresses (chunk-invariant); chunk advance = +32 u16 = 64 B
    const u16* xsrc[5]; u16* xdst[5];
#pragma unroll
    for (int k = 0; k < 5; ++k) {
        int g = tid + k * 256;
        int r = g >> 2, p = g & 3, s = p ^ ((r >> 1) & 3);
        if (g < XGRAN) { xsrc[k] = xbase + (size_t)r * CINP + s * 8; xdst[k] = xs + (size_t)(g & ~63) * 8; }
        else           { xsrc[k] = xbase;                            xdst[k] = xs; }
    }

    auto stage = [&](int bsel, int c) {
        const int ic  = c * 32;
        const int off = bsel * (XGRAN * 8);
#pragma unroll
        for (int k = 0; k < 5; ++k)
            if (tid + k * 256 < XGRAN) g2l16(xdst[k] + off, xsrc[k] + ic);
    };
    auto loadw = [&](bf16x8* dst, int tap, int c) {
#pragma unroll
        for (int mi = 0; mi < 4; ++mi)
            dst[mi] = *(const bf16x8*)(wfw + (size_t)((mi * 21 + tap * 7 + c) << 9));
    };

    bf16x8 acur[4], w1[4], w2[4];
    stage(0, 0);
    loadw(acur, 0, 0);
    __syncthreads();   // prologue: full drain once (buf0 + first A-frags ready)

#pragma unroll
    for (int c = 0; c < NCHUNK; ++c) {
        const u16* xb = xs + (c & 1) * (XGRAN * 8);
        // Issue order matters (in-order vmem completion):
        //   w1(4), w2(4)  [oldest]  ->  stage(4|5)  ->  [tap2] next acur(4) [newest]
        // so auto-waits for w1/w2 never drain stage, and the manual vmcnt(4)
        // at the barrier drains exactly stage while leaving next-acur in flight.
        loadw(w1, 1, c);
        loadw(w2, 2, c);
        if (c + 1 < NCHUNK) stage((c & 1) ^ 1, c + 1);

#pragma unroll
        for (int tap = 0; tap < 3; ++tap) {
            const bf16x8* af = (tap == 0) ? acur : (tap == 1) ? w1 : w2;
            if (tap == 2 && c + 1 < NCHUNK) loadw(acur, 0, c + 1);  // direct into acur (dead)
#pragma unroll
            for (int ti = 0; ti < 8; ++ti) {
                int row = wti + tap + ti * 16 + l;
                bf16x8 bv = *(const bf16x8*)(xb + ((size_t)row * 4 + (quad ^ ((row >> 1) & 3))) * 8);
                __builtin_amdgcn_s_setprio(1);
#pragma unroll
                for (int mi = 0; mi < 4; ++mi)
                    acc[mi][ti] = __builtin_amdgcn_mfma_f32_16x16x32_bf16(af[mi], bv, acc[mi][ti], 0, 0, 0);
                __builtin_amdgcn_s_setprio(0);
            }
        }

        if (c + 1 < NCHUNK) {
            // counted drain: stage loads (oldest) done; next-chunk W (newest, <=4) may fly
            asm volatile("s_waitcnt vmcnt(4)" ::: "memory");
            __builtin_amdgcn_s_barrier();
            __builtin_amdgcn_sched_barrier(0);
        }
    }

    // epilogue: +bias, sigmoid-form tanh-GELU (exp2-folded, branchless), f32 store
#pragma unroll
    for (int mi = 0; mi < 4; ++mi) {
        float bvv[4];
#pragma unroll
        for (int r = 0; r < 4; ++r)
            bvv[r] = bias[obase + wm + mi * 16 + quad * 4 + r];
#pragma unroll
        for (int ti = 0; ti < 8; ++ti) {
            int t = t0 + wti + ti * 16 + l;
#pragma unroll
            for (int r = 0; r < 4; ++r) {
                int m = wm + mi * 16 + quad * 4 + r;
                float v = acc[mi][ti][r] + bvv[r];
                float p2 = v * v;
                // exp(-z), z = v*(1.59577 + 0.0713548 v^2), folded to exp2
                float z2 = v * fmaf(p2, -0.10295089f, -2.30243665f);
                float e = __builtin_amdgcn_exp2f(z2);
                float g = v * __builtin_amdgcn_rcpf(1.0f + e);   // v * sigmoid(z)
                out[((size_t)(b * MD + m0 + m)) * T + t] = g;
            }
        }
    }
}

extern "C" void kernel_launch(void* const* d_in, const int* in_sizes, int n_in,
                              void* d_out, int out_size, void* d_ws, size_t ws_size,
                              hipStream_t stream) {
    const float* x    = (const float*)d_in[0];
    const int*   dsid = (const int*)d_in[1];
    const float* W    = (const float*)d_in[2];
    const float* bias = (const float*)d_in[3];
    float* out = (float*)d_out;

    u16* xt = (u16*)d_ws;                                // 32*1026*224*2 = 14.7 MB
    u16* wf = xt + (size_t)BATCH * XT_ROWS * CINP;       // 256*21*512*2  =  5.5 MB

    prep<<<512 + WOB, 256, 0, stream>>>(x, W, xt, wf);
    conv_mfma<<<512, 256, 0, stream>>>(xt, wf, dsid, bias, out);
}